// Round 5
// baseline (208.459 us; speedup 1.0000x reference)
//
#include <hip/hip_runtime.h>
#include <hip/hip_bf16.h>
#include <cstdint>
#include <cstddef>

#define N_NODES 50000
#define N_EDGES 800000
#define N_POS   200000
#define N_NEG   200000
#define DIM     128
#define NEG_SLOPE 0.2f

#define BUCK_SHIFT 7
#define BUCK_NODES 128                       // nodes per bucket (binning)
#define NBUCK 391                            // ceil(50000/128)
#define SLABCAP 2560                         // mean 2048, sigma 45 -> +11 sigma
#define BIN_CHUNK 4096
#define NB_BIN 196                           // ceil(800000/4096)

#define NSUB 8                               // aggregate blocks per bucket
#define SUB_NODES 16                         // nodes per aggregate block
#define SUBCAP 384                           // mean 256, sigma 16 -> +8 sigma

typedef _Float16 half8 __attribute__((ext_vector_type(8)));

// ---------------------------------------------------------------------------
// K1: feat = x @ W (fp32 compute, fp16 store) + fused el/er epilogue.
// ---------------------------------------------------------------------------
__global__ __launch_bounds__(256) void gemm_feat(
    const float* __restrict__ x, const float* __restrict__ W,
    const float* __restrict__ attn_l, const float* __restrict__ attn_r,
    half8* __restrict__ feat16, float* __restrict__ el, float* __restrict__ er,
    int n)
{
  __shared__ float xs[64][33];
  __shared__ float ws[32][128];
  const int tid = threadIdx.x;
  const int row0 = blockIdx.x * 64;
  const int rg = tid & 15;
  const int cg = tid >> 4;

  float acc[4][8];
#pragma unroll
  for (int i = 0; i < 4; ++i)
#pragma unroll
    for (int j = 0; j < 8; ++j) acc[i][j] = 0.f;

  for (int kc = 0; kc < DIM; kc += 32) {
    {
      const int r = tid >> 2;
      const int c = (tid & 3) * 8;
      const int grow = row0 + r;
      float4 v0 = make_float4(0.f, 0.f, 0.f, 0.f);
      float4 v1 = make_float4(0.f, 0.f, 0.f, 0.f);
      if (grow < n) {
        const float* srcp = &x[(size_t)grow * DIM + kc + c];
        v0 = *(const float4*)(srcp);
        v1 = *(const float4*)(srcp + 4);
      }
      xs[r][c + 0] = v0.x; xs[r][c + 1] = v0.y; xs[r][c + 2] = v0.z; xs[r][c + 3] = v0.w;
      xs[r][c + 4] = v1.x; xs[r][c + 5] = v1.y; xs[r][c + 6] = v1.z; xs[r][c + 7] = v1.w;
    }
    {
      const int r = tid >> 3;
      const int c = (tid & 7) * 16;
      const float* srcp = &W[(size_t)(kc + r) * DIM + c];
      *(float4*)&ws[r][c + 0]  = *(const float4*)(srcp + 0);
      *(float4*)&ws[r][c + 4]  = *(const float4*)(srcp + 4);
      *(float4*)&ws[r][c + 8]  = *(const float4*)(srcp + 8);
      *(float4*)&ws[r][c + 12] = *(const float4*)(srcp + 12);
    }
    __syncthreads();
#pragma unroll 8
    for (int k = 0; k < 32; ++k) {
      const float a0 = xs[rg * 4 + 0][k];
      const float a1 = xs[rg * 4 + 1][k];
      const float a2 = xs[rg * 4 + 2][k];
      const float a3 = xs[rg * 4 + 3][k];
      const float4 w0 = *(const float4*)&ws[k][cg * 8];
      const float4 w1 = *(const float4*)&ws[k][cg * 8 + 4];
      const float wv[8] = {w0.x, w0.y, w0.z, w0.w, w1.x, w1.y, w1.z, w1.w};
#pragma unroll
      for (int j = 0; j < 8; ++j) {
        acc[0][j] = fmaf(a0, wv[j], acc[0][j]);
        acc[1][j] = fmaf(a1, wv[j], acc[1][j]);
        acc[2][j] = fmaf(a2, wv[j], acc[2][j]);
        acc[3][j] = fmaf(a3, wv[j], acc[3][j]);
      }
    }
    __syncthreads();
  }

#pragma unroll
  for (int i = 0; i < 4; ++i) {
    const int grow = row0 + rg * 4 + i;
    if (grow < n) {
      half8 o;
#pragma unroll
      for (int j = 0; j < 8; ++j) o[j] = (_Float16)acc[i][j];
      feat16[(size_t)grow * 16 + cg] = o;
    }
  }

  const float4 al0 = *(const float4*)&attn_l[cg * 8];
  const float4 al1 = *(const float4*)&attn_l[cg * 8 + 4];
  const float4 ar0 = *(const float4*)&attn_r[cg * 8];
  const float4 ar1 = *(const float4*)&attn_r[cg * 8 + 4];
  const float alv[8] = {al0.x, al0.y, al0.z, al0.w, al1.x, al1.y, al1.z, al1.w};
  const float arv[8] = {ar0.x, ar0.y, ar0.z, ar0.w, ar1.x, ar1.y, ar1.z, ar1.w};
  float* redl = &ws[0][0];   // reuse: 2*64*17 = 2176 floats <= 4096
  float* redr = redl + 64 * 17;
#pragma unroll
  for (int i = 0; i < 4; ++i) {
    float pl = 0.f, pr = 0.f;
#pragma unroll
    for (int j = 0; j < 8; ++j) {
      pl = fmaf(acc[i][j], alv[j], pl);
      pr = fmaf(acc[i][j], arv[j], pr);
    }
    redl[(rg * 4 + i) * 17 + cg] = pl;
    redr[(rg * 4 + i) * 17 + cg] = pr;
  }
  __syncthreads();
  if (tid < 64) {
    const int grow = row0 + tid;
    if (grow < n) {
      float sl = 0.f, sr = 0.f;
#pragma unroll
      for (int c = 0; c < 16; ++c) {
        sl += redl[tid * 17 + c];
        sr += redr[tid * 17 + c];
      }
      el[grow] = sl;
      er[grow] = sr;
    }
  }
}

// ---------------------------------------------------------------------------
// K2: bucket binning into 128-node fixed-cap slabs.
// Record: (src << 7) | (dst & 127).
// ---------------------------------------------------------------------------
__global__ __launch_bounds__(256) void bin_kernel(
    const int* __restrict__ src, const int* __restrict__ dst,
    unsigned int* __restrict__ slab, int* __restrict__ slab_cursor)
{
  __shared__ int hist[NBUCK];
  __shared__ int base_s[NBUCK];
  __shared__ int cur[NBUCK];
  const int tid = threadIdx.x;
  const int e0 = blockIdx.x * BIN_CHUNK;
  for (int i = tid; i < NBUCK; i += 256) { hist[i] = 0; cur[i] = 0; }
  __syncthreads();
  for (int i = tid; i < BIN_CHUNK; i += 256) {
    const int e = e0 + i;
    if (e < N_EDGES) atomicAdd(&hist[dst[e] >> BUCK_SHIFT], 1);
  }
  __syncthreads();
  for (int i = tid; i < NBUCK; i += 256) {
    const int h = hist[i];
    base_s[i] = h ? atomicAdd(&slab_cursor[i], h) : 0;
  }
  __syncthreads();
  for (int i = tid; i < BIN_CHUNK; i += 256) {
    const int e = e0 + i;
    if (e >= N_EDGES) continue;
    const int d = dst[e];
    const int bk = d >> BUCK_SHIFT;
    const int p = atomicAdd(&cur[bk], 1);
    int idx = base_s[bk] + p;
    if (idx >= SLABCAP) idx = SLABCAP - 1;   // statistically never
    slab[(size_t)bk * SLABCAP + idx] =
        ((unsigned int)src[e] << BUCK_SHIFT) | (unsigned int)(d & (BUCK_NODES - 1));
  }
}

// ---------------------------------------------------------------------------
// K3: aggregation.  8 blocks per bucket (16-node sub-ranges, 3128 blocks);
// one node per 16-lane quarter-wave; feat16 gather loop unrolled x8.
// ---------------------------------------------------------------------------
__global__ __launch_bounds__(256) void aggregate_kernel(
    const half8* __restrict__ feat16, const float* __restrict__ el,
    const float* __restrict__ er,
    const unsigned int* __restrict__ slab, const int* __restrict__ slab_cursor,
    const float* __restrict__ bias, half8* __restrict__ h16)
{
  __shared__ unsigned int csr[SUBCAP];
  __shared__ float wbuf[SUBCAP];
  __shared__ int cnt_l[SUB_NODES];
  __shared__ int start_l[SUB_NODES];
  __shared__ int cur_l[SUB_NODES];
  const int b = blockIdx.x >> 3;            // bucket
  const int sub = blockIdx.x & 7;           // 16-node sub-range
  const int tid = threadIdx.x;
  const int cnt = min(slab_cursor[b], SLABCAP);
  const unsigned int* sb = slab + (size_t)b * SLABCAP;
  const int node0 = (b << BUCK_SHIFT) + sub * SUB_NODES;

  if (tid < SUB_NODES) cnt_l[tid] = 0;
  __syncthreads();
  for (int i = tid; i < cnt; i += 256) {
    const int d = sb[i] & (BUCK_NODES - 1);
    if ((d >> 4) == sub) atomicAdd(&cnt_l[d & 15], 1);
  }
  __syncthreads();
  if (tid < 64) {
    const int v = (tid < SUB_NODES) ? cnt_l[tid] : 0;
    int inc = v;
#pragma unroll
    for (int d = 1; d < 16; d <<= 1) {
      const int t = __shfl_up(inc, d, 64);
      if (tid >= d) inc += t;
    }
    if (tid < SUB_NODES) { start_l[tid] = inc - v; cur_l[tid] = 0; }
  }
  __syncthreads();
  for (int i = tid; i < cnt; i += 256) {
    const unsigned int r = sb[i];
    const int d = r & (BUCK_NODES - 1);
    if ((d >> 4) == sub) {
      const int p = atomicAdd(&cur_l[d & 15], 1);
      const int idx = start_l[d & 15] + p;
      if (idx < SUBCAP) csr[idx] = r;
    }
  }
  __syncthreads();

  const int lane = tid & 63;
  const int ql = lane & 15;
  const int qid = (tid >> 6) * 4 + (lane >> 4);  // 0..15 -> this quarter's node
  const float4 b0 = *(const float4*)&bias[ql * 8];
  const float4 b1 = *(const float4*)&bias[ql * 8 + 4];
  const float bb[8] = {b0.x, b0.y, b0.z, b0.w, b1.x, b1.y, b1.z, b1.w};

  const int nl = qid;
  const int node = node0 + nl;
  if (node < N_NODES) {
    const int beg = start_l[nl];
    const int cnum = cnt_l[nl];
    const float ern = er[node];

    // pass 1: e -> LDS, running max (16-wide over edges)
    float m = -INFINITY;
    for (int c = ql; c < cnum; c += 16) {
      const unsigned int r = csr[beg + c];
      const float v = el[r >> BUCK_SHIFT] + ern;
      const float e = (v > 0.f) ? v : NEG_SLOPE * v;
      wbuf[beg + c] = e;
      m = fmaxf(m, e);
    }
#pragma unroll
    for (int o = 1; o < 16; o <<= 1) m = fmaxf(m, __shfl_xor(m, o, 64));

    // pass 1.5: w = exp(e-m) -> LDS, partial sum
    float sp = 0.f;
    for (int c = ql; c < cnum; c += 16) {
      const float w = __expf(wbuf[beg + c] - m);
      wbuf[beg + c] = w;
      sp += w;
    }
#pragma unroll
    for (int o = 1; o < 16; o <<= 1) sp += __shfl_xor(sp, o, 64);

    // pass 2: gather-accumulate, unrolled x8 for MLP
    float acc[8];
#pragma unroll
    for (int k = 0; k < 8; ++k) acc[k] = 0.f;
    int t = 0;
    for (; t + 8 <= cnum; t += 8) {
      float wv[8]; int sv[8]; half8 fv[8];
#pragma unroll
      for (int u = 0; u < 8; ++u) {
        wv[u] = wbuf[beg + t + u];
        sv[u] = (int)(csr[beg + t + u] >> BUCK_SHIFT);
      }
#pragma unroll
      for (int u = 0; u < 8; ++u) fv[u] = feat16[(size_t)sv[u] * 16 + ql];
#pragma unroll
      for (int u = 0; u < 8; ++u)
#pragma unroll
        for (int k = 0; k < 8; ++k) acc[k] = fmaf(wv[u], (float)fv[u][k], acc[k]);
    }
    for (; t + 4 <= cnum; t += 4) {
      float wv[4]; int sv[4]; half8 fv[4];
#pragma unroll
      for (int u = 0; u < 4; ++u) {
        wv[u] = wbuf[beg + t + u];
        sv[u] = (int)(csr[beg + t + u] >> BUCK_SHIFT);
      }
#pragma unroll
      for (int u = 0; u < 4; ++u) fv[u] = feat16[(size_t)sv[u] * 16 + ql];
#pragma unroll
      for (int u = 0; u < 4; ++u)
#pragma unroll
        for (int k = 0; k < 8; ++k) acc[k] = fmaf(wv[u], (float)fv[u][k], acc[k]);
    }
    for (; t < cnum; ++t) {
      const float w = wbuf[beg + t];
      const int sid = (int)(csr[beg + t] >> BUCK_SHIFT);
      const half8 f = feat16[(size_t)sid * 16 + ql];
#pragma unroll
      for (int k = 0; k < 8; ++k) acc[k] = fmaf(w, (float)f[k], acc[k]);
    }

    const float inv = (cnum > 0) ? 1.f / sp : 0.f;
    half8 o;
#pragma unroll
    for (int k = 0; k < 8; ++k)
      o[k] = (_Float16)fmaxf(acc[k] * inv + bb[k], 0.f);
    h16[(size_t)node * 16 + ql] = o;
  }
}

// ---------------------------------------------------------------------------
// K4: scores.  4 pairs per quarter-wave (16 pairs/wave) -> 8 row loads in
// flight per lane.  fp16 rows, 16B loads.
// ---------------------------------------------------------------------------
__global__ __launch_bounds__(256) void score_kernel(
    const half8* __restrict__ h16,
    const int* __restrict__ pos_src, const int* __restrict__ pos_dst,
    const int* __restrict__ neg_src, const int* __restrict__ neg_dst,
    float* __restrict__ out, int ntot)
{
  const int wid = (int)((blockIdx.x * blockDim.x + threadIdx.x) >> 6);
  const int lane = threadIdx.x & 63;
  const int q = lane >> 4;
  const int ql = lane & 15;
  const int base = (wid * 4 + q) * 4;       // first of this quarter's 4 pairs

  int av[4], bv[4];
#pragma unroll
  for (int u = 0; u < 4; ++u) {
    const int p = base + u;
    int a = 0, b = 0;
    if (p < N_POS)      { a = pos_src[p]; b = pos_dst[p]; }
    else if (p < ntot)  { a = neg_src[p - N_POS]; b = neg_dst[p - N_POS]; }
    av[u] = a; bv[u] = b;
  }
  half8 ha[4], hb[4];
#pragma unroll
  for (int u = 0; u < 4; ++u) {
    ha[u] = h16[(size_t)av[u] * 16 + ql];
    hb[u] = h16[(size_t)bv[u] * 16 + ql];
  }
  float sum[4];
#pragma unroll
  for (int u = 0; u < 4; ++u) {
    float s = 0.f;
#pragma unroll
    for (int k = 0; k < 8; ++k) s = fmaf((float)ha[u][k], (float)hb[u][k], s);
#pragma unroll
    for (int o = 8; o > 0; o >>= 1) s += __shfl_xor(s, o, 64);
    sum[u] = s;
  }
  if (ql == 0) {
#pragma unroll
    for (int u = 0; u < 4; ++u) {
      const int p = base + u;
      if (p < ntot) out[p] = sum[u];
    }
  }
}

// ---------------------------------------------------------------------------
extern "C" void kernel_launch(void* const* d_in, const int* in_sizes, int n_in,
                              void* d_out, int out_size, void* d_ws, size_t ws_size,
                              hipStream_t stream) {
  const float* x      = (const float*)d_in[0];
  const float* W      = (const float*)d_in[1];
  const float* attn_l = (const float*)d_in[2];
  const float* attn_r = (const float*)d_in[3];
  const float* bias   = (const float*)d_in[4];
  const int* src      = (const int*)d_in[5];
  const int* dst      = (const int*)d_in[6];
  const int* pos_src  = (const int*)d_in[7];
  const int* pos_dst  = (const int*)d_in[8];
  const int* neg_src  = (const int*)d_in[9];
  const int* neg_dst  = (const int*)d_in[10];
  float* out = (float*)d_out;

  char* ws = (char*)d_ws;
  const size_t F16B = (size_t)N_NODES * DIM * sizeof(_Float16);  // 12.8 MB
  half8* feat16          = (half8*)(ws);
  half8* h16             = (half8*)(ws + F16B);
  float* el              = (float*)(ws + 2 * F16B);
  float* er              = (float*)(ws + 2 * F16B + 200000);
  int*   slab_cursor     = (int*)  (ws + 2 * F16B + 400000);
  unsigned int* slab     = (unsigned int*)(ws + 2 * F16B + 401664);

  hipMemsetAsync(slab_cursor, 0, NBUCK * sizeof(int), stream);

  gemm_feat<<<(N_NODES + 63) / 64, 256, 0, stream>>>(
      x, W, attn_l, attn_r, feat16, el, er, N_NODES);
  bin_kernel<<<NB_BIN, 256, 0, stream>>>(src, dst, slab, slab_cursor);
  aggregate_kernel<<<NBUCK * NSUB, 256, 0, stream>>>(
      feat16, el, er, slab, slab_cursor, bias, h16);
  score_kernel<<<((N_POS + N_NEG + 15) / 16 + 3) / 4, 256, 0, stream>>>(
      h16, pos_src, pos_dst, neg_src, neg_dst, out, N_POS + N_NEG);
}

// Round 6
// 202.785 us; speedup vs baseline: 1.0280x; 1.0280x over previous
//
#include <hip/hip_runtime.h>
#include <hip/hip_bf16.h>
#include <cstdint>
#include <cstddef>

#define N_NODES 50000
#define N_EDGES 800000
#define N_POS   200000
#define N_NEG   200000
#define DIM     128
#define NEG_SLOPE 0.2f

#define BUCK_SHIFT 5
#define BUCK_NODES 32                        // nodes per bucket
#define NBUCK 1563                           // ceil(50000/32)
#define SLABCAP 768                          // mean 512, sigma 22.6 -> +11 sigma
#define BIN_CHUNK 4096
#define NB_BIN 196                           // ceil(800000/4096)

typedef _Float16 half8 __attribute__((ext_vector_type(8)));

// ---------------------------------------------------------------------------
// K1: feat = x @ W (fp32 compute, fp16 store) + fused el/er epilogue.
// ---------------------------------------------------------------------------
__global__ __launch_bounds__(256) void gemm_feat(
    const float* __restrict__ x, const float* __restrict__ W,
    const float* __restrict__ attn_l, const float* __restrict__ attn_r,
    half8* __restrict__ feat16, float* __restrict__ el, float* __restrict__ er,
    int n)
{
  __shared__ float xs[64][33];
  __shared__ float ws[32][128];
  const int tid = threadIdx.x;
  const int row0 = blockIdx.x * 64;
  const int rg = tid & 15;
  const int cg = tid >> 4;

  float acc[4][8];
#pragma unroll
  for (int i = 0; i < 4; ++i)
#pragma unroll
    for (int j = 0; j < 8; ++j) acc[i][j] = 0.f;

  for (int kc = 0; kc < DIM; kc += 32) {
    {
      const int r = tid >> 2;
      const int c = (tid & 3) * 8;
      const int grow = row0 + r;
      float4 v0 = make_float4(0.f, 0.f, 0.f, 0.f);
      float4 v1 = make_float4(0.f, 0.f, 0.f, 0.f);
      if (grow < n) {
        const float* srcp = &x[(size_t)grow * DIM + kc + c];
        v0 = *(const float4*)(srcp);
        v1 = *(const float4*)(srcp + 4);
      }
      xs[r][c + 0] = v0.x; xs[r][c + 1] = v0.y; xs[r][c + 2] = v0.z; xs[r][c + 3] = v0.w;
      xs[r][c + 4] = v1.x; xs[r][c + 5] = v1.y; xs[r][c + 6] = v1.z; xs[r][c + 7] = v1.w;
    }
    {
      const int r = tid >> 3;
      const int c = (tid & 7) * 16;
      const float* srcp = &W[(size_t)(kc + r) * DIM + c];
      *(float4*)&ws[r][c + 0]  = *(const float4*)(srcp + 0);
      *(float4*)&ws[r][c + 4]  = *(const float4*)(srcp + 4);
      *(float4*)&ws[r][c + 8]  = *(const float4*)(srcp + 8);
      *(float4*)&ws[r][c + 12] = *(const float4*)(srcp + 12);
    }
    __syncthreads();
#pragma unroll 8
    for (int k = 0; k < 32; ++k) {
      const float a0 = xs[rg * 4 + 0][k];
      const float a1 = xs[rg * 4 + 1][k];
      const float a2 = xs[rg * 4 + 2][k];
      const float a3 = xs[rg * 4 + 3][k];
      const float4 w0 = *(const float4*)&ws[k][cg * 8];
      const float4 w1 = *(const float4*)&ws[k][cg * 8 + 4];
      const float wv[8] = {w0.x, w0.y, w0.z, w0.w, w1.x, w1.y, w1.z, w1.w};
#pragma unroll
      for (int j = 0; j < 8; ++j) {
        acc[0][j] = fmaf(a0, wv[j], acc[0][j]);
        acc[1][j] = fmaf(a1, wv[j], acc[1][j]);
        acc[2][j] = fmaf(a2, wv[j], acc[2][j]);
        acc[3][j] = fmaf(a3, wv[j], acc[3][j]);
      }
    }
    __syncthreads();
  }

#pragma unroll
  for (int i = 0; i < 4; ++i) {
    const int grow = row0 + rg * 4 + i;
    if (grow < n) {
      half8 o;
#pragma unroll
      for (int j = 0; j < 8; ++j) o[j] = (_Float16)acc[i][j];
      feat16[(size_t)grow * 16 + cg] = o;
    }
  }

  const float4 al0 = *(const float4*)&attn_l[cg * 8];
  const float4 al1 = *(const float4*)&attn_l[cg * 8 + 4];
  const float4 ar0 = *(const float4*)&attn_r[cg * 8];
  const float4 ar1 = *(const float4*)&attn_r[cg * 8 + 4];
  const float alv[8] = {al0.x, al0.y, al0.z, al0.w, al1.x, al1.y, al1.z, al1.w};
  const float arv[8] = {ar0.x, ar0.y, ar0.z, ar0.w, ar1.x, ar1.y, ar1.z, ar1.w};
  float* redl = &ws[0][0];   // reuse: 2*64*17 = 2176 floats <= 4096
  float* redr = redl + 64 * 17;
#pragma unroll
  for (int i = 0; i < 4; ++i) {
    float pl = 0.f, pr = 0.f;
#pragma unroll
    for (int j = 0; j < 8; ++j) {
      pl = fmaf(acc[i][j], alv[j], pl);
      pr = fmaf(acc[i][j], arv[j], pr);
    }
    redl[(rg * 4 + i) * 17 + cg] = pl;
    redr[(rg * 4 + i) * 17 + cg] = pr;
  }
  __syncthreads();
  if (tid < 64) {
    const int grow = row0 + tid;
    if (grow < n) {
      float sl = 0.f, sr = 0.f;
#pragma unroll
      for (int c = 0; c < 16; ++c) {
        sl += redl[tid * 17 + c];
        sr += redr[tid * 17 + c];
      }
      el[grow] = sl;
      er[grow] = sr;
    }
  }
}

// ---------------------------------------------------------------------------
// K2: bucket binning into 32-node fixed-cap slabs (1563 buckets).
// Record: (src << 5) | (dst & 31).
// ---------------------------------------------------------------------------
__global__ __launch_bounds__(256) void bin_kernel(
    const int* __restrict__ src, const int* __restrict__ dst,
    unsigned int* __restrict__ slab, int* __restrict__ slab_cursor)
{
  __shared__ int hist[NBUCK];
  __shared__ int base_s[NBUCK];
  __shared__ int cur[NBUCK];
  const int tid = threadIdx.x;
  const int e0 = blockIdx.x * BIN_CHUNK;
  for (int i = tid; i < NBUCK; i += 256) { hist[i] = 0; cur[i] = 0; }
  __syncthreads();
  for (int i = tid; i < BIN_CHUNK; i += 256) {
    const int e = e0 + i;
    if (e < N_EDGES) atomicAdd(&hist[dst[e] >> BUCK_SHIFT], 1);
  }
  __syncthreads();
  for (int i = tid; i < NBUCK; i += 256) {
    const int h = hist[i];
    base_s[i] = h ? atomicAdd(&slab_cursor[i], h) : 0;
  }
  __syncthreads();
  for (int i = tid; i < BIN_CHUNK; i += 256) {
    const int e = e0 + i;
    if (e >= N_EDGES) continue;
    const int d = dst[e];
    const int bk = d >> BUCK_SHIFT;
    const int p = atomicAdd(&cur[bk], 1);
    int idx = base_s[bk] + p;
    if (idx >= SLABCAP) idx = SLABCAP - 1;   // statistically never
    slab[(size_t)bk * SLABCAP + idx] =
        ((unsigned int)src[e] << BUCK_SHIFT) | (unsigned int)(d & (BUCK_NODES - 1));
  }
}

// ---------------------------------------------------------------------------
// K3: aggregation.  One block per 32-node bucket (1563 blocks) — slab is
// exactly this block's records (no filter redundancy).  LDS sort by exact
// dst, then 16-lane quarter-waves own 2 nodes each.  Single fused pass:
// no max-subtraction (exp(e)/sum(exp(e)) is identical), w computed 16-wide
// then shfl-broadcast, feat16 gather unrolled x4.
// ---------------------------------------------------------------------------
__global__ __launch_bounds__(256) void aggregate_kernel(
    const half8* __restrict__ feat16, const float* __restrict__ el,
    const float* __restrict__ er,
    const unsigned int* __restrict__ slab, const int* __restrict__ slab_cursor,
    const float* __restrict__ bias, half8* __restrict__ h16)
{
  __shared__ unsigned int csr[SLABCAP];
  __shared__ int cnt_l[BUCK_NODES];
  __shared__ int start_l[BUCK_NODES];
  __shared__ int cur_l[BUCK_NODES];
  const int b = blockIdx.x;
  const int tid = threadIdx.x;
  const int cnt = min(slab_cursor[b], SLABCAP);
  const unsigned int* sb = slab + (size_t)b * SLABCAP;
  const int node0 = b << BUCK_SHIFT;

  if (tid < BUCK_NODES) cnt_l[tid] = 0;
  __syncthreads();
  for (int i = tid; i < cnt; i += 256)
    atomicAdd(&cnt_l[sb[i] & (BUCK_NODES - 1)], 1);
  __syncthreads();
  if (tid < 64) {
    const int v = (tid < BUCK_NODES) ? cnt_l[tid] : 0;
    int inc = v;
#pragma unroll
    for (int d = 1; d < 32; d <<= 1) {
      const int t = __shfl_up(inc, d, 64);
      if (tid >= d) inc += t;
    }
    if (tid < BUCK_NODES) { start_l[tid] = inc - v; cur_l[tid] = 0; }
  }
  __syncthreads();
  for (int i = tid; i < cnt; i += 256) {
    const unsigned int r = sb[i];
    const int p = atomicAdd(&cur_l[r & (BUCK_NODES - 1)], 1);
    csr[start_l[r & (BUCK_NODES - 1)] + p] = r;
  }
  __syncthreads();

  const int lane = tid & 63;
  const int ql = lane & 15;
  const int qb = lane & 48;                      // quarter base lane
  const int qid = (tid >> 6) * 4 + (lane >> 4);  // 0..15
  const float4 b0 = *(const float4*)&bias[ql * 8];
  const float4 b1 = *(const float4*)&bias[ql * 8 + 4];
  const float bb[8] = {b0.x, b0.y, b0.z, b0.w, b1.x, b1.y, b1.z, b1.w};

  for (int nl = qid; nl < BUCK_NODES; nl += 16) {
    const int node = node0 + nl;
    if (node >= N_NODES) break;
    const int beg = start_l[nl];
    const int c = cnt_l[nl];
    const float ern = er[node];

    float sp = 0.f;
    float acc[8];
#pragma unroll
    for (int k = 0; k < 8; ++k) acc[k] = 0.f;

    for (int t0 = 0; t0 < c; t0 += 16) {
      // step A (16-wide): w for up to 16 records
      const int t = t0 + ql;
      const unsigned int r = csr[beg + ((t < c) ? t : (c - 1))];
      const int sid = (int)(r >> BUCK_SHIFT);
      float w = 0.f;
      if (t < c) {
        const float v = el[sid] + ern;
        const float e = (v > 0.f) ? v : NEG_SLOPE * v;
        w = __expf(e);
      }
      sp += w;
      // step B: broadcast each record, gather its feat row, accumulate
      const int nb = min(16, c - t0);
      int j = 0;
      for (; j + 4 <= nb; j += 4) {
        float wv[4]; int sv[4]; half8 fv[4];
#pragma unroll
        for (int u = 0; u < 4; ++u) {
          wv[u] = __shfl(w, qb + j + u, 64);
          sv[u] = __shfl(sid, qb + j + u, 64);
        }
#pragma unroll
        for (int u = 0; u < 4; ++u) fv[u] = feat16[(size_t)sv[u] * 16 + ql];
#pragma unroll
        for (int u = 0; u < 4; ++u)
#pragma unroll
          for (int k = 0; k < 8; ++k)
            acc[k] = fmaf(wv[u], (float)fv[u][k], acc[k]);
      }
      for (; j < nb; ++j) {
        const float wj = __shfl(w, qb + j, 64);
        const int sj = __shfl(sid, qb + j, 64);
        const half8 f = feat16[(size_t)sj * 16 + ql];
#pragma unroll
        for (int k = 0; k < 8; ++k) acc[k] = fmaf(wj, (float)f[k], acc[k]);
      }
    }

    // reduce sp across the 16 lanes of this quarter
#pragma unroll
    for (int o = 1; o < 16; o <<= 1) sp += __shfl_xor(sp, o, 64);

    const float inv = (c > 0) ? 1.f / sp : 0.f;
    half8 o;
#pragma unroll
    for (int k = 0; k < 8; ++k)
      o[k] = (_Float16)fmaxf(acc[k] * inv + bb[k], 0.f);
    h16[(size_t)node * 16 + ql] = o;
  }
}

// ---------------------------------------------------------------------------
// K4: scores.  4 pairs per quarter-wave (16 pairs/wave) -> 8 row loads in
// flight per lane.  fp16 rows, 16B loads.
// ---------------------------------------------------------------------------
__global__ __launch_bounds__(256) void score_kernel(
    const half8* __restrict__ h16,
    const int* __restrict__ pos_src, const int* __restrict__ pos_dst,
    const int* __restrict__ neg_src, const int* __restrict__ neg_dst,
    float* __restrict__ out, int ntot)
{
  const int wid = (int)((blockIdx.x * blockDim.x + threadIdx.x) >> 6);
  const int lane = threadIdx.x & 63;
  const int q = lane >> 4;
  const int ql = lane & 15;
  const int base = (wid * 4 + q) * 4;

  int av[4], bv[4];
#pragma unroll
  for (int u = 0; u < 4; ++u) {
    const int p = base + u;
    int a = 0, b = 0;
    if (p < N_POS)      { a = pos_src[p]; b = pos_dst[p]; }
    else if (p < ntot)  { a = neg_src[p - N_POS]; b = neg_dst[p - N_POS]; }
    av[u] = a; bv[u] = b;
  }
  half8 ha[4], hb[4];
#pragma unroll
  for (int u = 0; u < 4; ++u) {
    ha[u] = h16[(size_t)av[u] * 16 + ql];
    hb[u] = h16[(size_t)bv[u] * 16 + ql];
  }
  float sum[4];
#pragma unroll
  for (int u = 0; u < 4; ++u) {
    float s = 0.f;
#pragma unroll
    for (int k = 0; k < 8; ++k) s = fmaf((float)ha[u][k], (float)hb[u][k], s);
#pragma unroll
    for (int o = 8; o > 0; o >>= 1) s += __shfl_xor(s, o, 64);
    sum[u] = s;
  }
  if (ql == 0) {
#pragma unroll
    for (int u = 0; u < 4; ++u) {
      const int p = base + u;
      if (p < ntot) out[p] = sum[u];
    }
  }
}

// ---------------------------------------------------------------------------
extern "C" void kernel_launch(void* const* d_in, const int* in_sizes, int n_in,
                              void* d_out, int out_size, void* d_ws, size_t ws_size,
                              hipStream_t stream) {
  const float* x      = (const float*)d_in[0];
  const float* W      = (const float*)d_in[1];
  const float* attn_l = (const float*)d_in[2];
  const float* attn_r = (const float*)d_in[3];
  const float* bias   = (const float*)d_in[4];
  const int* src      = (const int*)d_in[5];
  const int* dst      = (const int*)d_in[6];
  const int* pos_src  = (const int*)d_in[7];
  const int* pos_dst  = (const int*)d_in[8];
  const int* neg_src  = (const int*)d_in[9];
  const int* neg_dst  = (const int*)d_in[10];
  float* out = (float*)d_out;

  char* ws = (char*)d_ws;
  const size_t F16B = (size_t)N_NODES * DIM * sizeof(_Float16);  // 12.8 MB
  half8* feat16          = (half8*)(ws);
  half8* h16             = (half8*)(ws + F16B);
  float* el              = (float*)(ws + 2 * F16B);
  float* er              = (float*)(ws + 2 * F16B + 200000);
  int*   slab_cursor     = (int*)  (ws + 2 * F16B + 400000);
  unsigned int* slab     = (unsigned int*)(ws + 2 * F16B + 406656);

  hipMemsetAsync(slab_cursor, 0, NBUCK * sizeof(int), stream);

  gemm_feat<<<(N_NODES + 63) / 64, 256, 0, stream>>>(
      x, W, attn_l, attn_r, feat16, el, er, N_NODES);
  bin_kernel<<<NB_BIN, 256, 0, stream>>>(src, dst, slab, slab_cursor);
  aggregate_kernel<<<NBUCK, 256, 0, stream>>>(
      feat16, el, er, slab, slab_cursor, bias, h16);
  score_kernel<<<((N_POS + N_NEG + 15) / 16 + 3) / 4, 256, 0, stream>>>(
      h16, pos_src, pos_dst, neg_src, neg_dst, out, N_POS + N_NEG);
}

// Round 7
// 201.138 us; speedup vs baseline: 1.0364x; 1.0082x over previous
//
#include <hip/hip_runtime.h>
#include <hip/hip_bf16.h>
#include <cstdint>
#include <cstddef>

#define N_NODES 50000
#define N_EDGES 800000
#define N_POS   200000
#define N_NEG   200000
#define DIM     128
#define NEG_SLOPE 0.2f

#define BUCK_SHIFT 5
#define BUCK_NODES 32                        // nodes per bucket
#define NBUCK 1563                           // ceil(50000/32)
#define SLABCAP 768                          // mean 512, sigma 22.6 -> +11 sigma
#define BIN_CHUNK 8192
#define NB_BIN 98                            // ceil(800000/8192)

typedef _Float16 half8 __attribute__((ext_vector_type(8)));
typedef float    floatx4 __attribute__((ext_vector_type(4)));

// ---------------------------------------------------------------------------
// K1: feat = x @ W via MFMA fp16 (fp32 accumulate) + fused el/er epilogue.
// Block = 64 rows x 128 cols, 4 waves x 16 rows.  LDS tiles use a 16B-chunk
// XOR swizzle (chunk ^ (row&15)) so fragment ds_read_b128 is ~conflict-free.
// A-frag: A[m=lane&15][k=quad*8+j]; C/D: col=lane&15, row=quad*4+reg.
// ---------------------------------------------------------------------------
__global__ __launch_bounds__(256) void gemm_feat(
    const float* __restrict__ x, const float* __restrict__ W,
    const float* __restrict__ attn_l, const float* __restrict__ attn_r,
    half8* __restrict__ feat16, float* __restrict__ el, float* __restrict__ er,
    int n)
{
  __shared__ _Float16 xt[64 * 128];    // 16 KB, swizzled [row][k]
  __shared__ _Float16 wt[128 * 128];   // 32 KB, swizzled [n][k]  (W^T)
  const int tid = threadIdx.x;
  const int row0 = blockIdx.x * 64;
  const int lane = tid & 63;
  const int wv = tid >> 6;             // wave id 0..3 -> rows [16wv,16wv+16)
  const int ql = lane & 15;
  const int quad = lane >> 4;

  // ---- stage W^T (fp32 -> fp16), transposed scatter into swizzled wt ----
  {
    const int k = tid >> 1;            // 0..127
    const int n0 = (tid & 1) * 64;
#pragma unroll 4
    for (int j = 0; j < 64; j += 4) {
      const float4 v = *(const float4*)&W[(size_t)k * DIM + n0 + j];
      const float vv[4] = {v.x, v.y, v.z, v.w};
#pragma unroll
      for (int u = 0; u < 4; ++u) {
        const int nn = n0 + j + u;
        wt[nn * 128 + ((((k >> 3) ^ (nn & 15)) << 3) | (k & 7))] = (_Float16)vv[u];
      }
    }
  }
  // ---- stage x tile (fp32 -> fp16) into swizzled xt ----
  {
    const int r = tid >> 2;
    const int grow = row0 + r;
    const int c0 = (tid & 3) * 32;
#pragma unroll
    for (int cc = 0; cc < 32; cc += 8) {
      const int c = c0 + cc;
      float4 v0 = make_float4(0.f, 0.f, 0.f, 0.f);
      float4 v1 = make_float4(0.f, 0.f, 0.f, 0.f);
      if (grow < n) {
        const float* sp = &x[(size_t)grow * DIM + c];
        v0 = *(const float4*)(sp);
        v1 = *(const float4*)(sp + 4);
      }
      half8 h;
      h[0] = (_Float16)v0.x; h[1] = (_Float16)v0.y;
      h[2] = (_Float16)v0.z; h[3] = (_Float16)v0.w;
      h[4] = (_Float16)v1.x; h[5] = (_Float16)v1.y;
      h[6] = (_Float16)v1.z; h[7] = (_Float16)v1.w;
      const int chunk = c >> 3;
      *(half8*)&xt[r * 128 + ((chunk ^ (r & 15)) << 3)] = h;
    }
  }
  __syncthreads();

  // ---- MFMA: 8 N-tiles x 4 K-steps ----
  floatx4 acc[8];
#pragma unroll
  for (int t = 0; t < 8; ++t) acc[t] = (floatx4){0.f, 0.f, 0.f, 0.f};

  const int arow = wv * 16 + ql;       // arow & 15 == ql
  half8 af[4];
#pragma unroll
  for (int s = 0; s < 4; ++s) {
    const int chunk = s * 4 + quad;
    af[s] = *(half8*)&xt[arow * 128 + ((chunk ^ ql) << 3)];
  }
#pragma unroll
  for (int t = 0; t < 8; ++t) {
    const int brow = t * 16 + ql;      // brow & 15 == ql
#pragma unroll
    for (int s = 0; s < 4; ++s) {
      const int chunk = s * 4 + quad;
      const half8 bf = *(half8*)&wt[brow * 128 + ((chunk ^ ql) << 3)];
      acc[t] = __builtin_amdgcn_mfma_f32_16x16x32_f16(af[s], bf, acc[t], 0, 0, 0);
    }
  }

  // ---- fused el/er: col = 16t+ql, row = 16wv + 4quad + reg ----
  {
    float al8[8], ar8[8];
#pragma unroll
    for (int t = 0; t < 8; ++t) {
      al8[t] = attn_l[t * 16 + ql];
      ar8[t] = attn_r[t * 16 + ql];
    }
    float pl[4] = {0.f, 0.f, 0.f, 0.f};
    float pr[4] = {0.f, 0.f, 0.f, 0.f};
#pragma unroll
    for (int t = 0; t < 8; ++t)
#pragma unroll
      for (int r = 0; r < 4; ++r) {
        pl[r] = fmaf(acc[t][r], al8[t], pl[r]);
        pr[r] = fmaf(acc[t][r], ar8[t], pr[r]);
      }
#pragma unroll
    for (int o = 1; o < 16; o <<= 1)
#pragma unroll
      for (int r = 0; r < 4; ++r) {
        pl[r] += __shfl_xor(pl[r], o, 64);
        pr[r] += __shfl_xor(pr[r], o, 64);
      }
    if (ql == 0) {
#pragma unroll
      for (int r = 0; r < 4; ++r) {
        const int grow = row0 + wv * 16 + quad * 4 + r;
        if (grow < n) { el[grow] = pl[r]; er[grow] = pr[r]; }
      }
    }
  }

  // ---- feat16 store via LDS bounce (each wave touches only its own rows) --
#pragma unroll
  for (int t = 0; t < 8; ++t)
#pragma unroll
    for (int r = 0; r < 4; ++r)
      xt[(wv * 16 + quad * 4 + r) * 128 + t * 16 + ql] = (_Float16)acc[t][r];
  __syncthreads();
  {
    const int r = tid >> 2;
    const int grow = row0 + r;
    if (grow < n) {
      const int c0 = (tid & 3) * 32;
#pragma unroll
      for (int cc = 0; cc < 32; cc += 8) {
        const half8 h = *(half8*)&xt[r * 128 + c0 + cc];
        feat16[(size_t)grow * 16 + ((c0 + cc) >> 3)] = h;
      }
    }
  }
}

// ---------------------------------------------------------------------------
// K2: bucket binning into 32-node fixed-cap slabs (1563 buckets).
// Record: (src << 5) | (dst & 31).  8192-edge chunks -> longer runs, fewer
// cross-XCD cursor atomics.
// ---------------------------------------------------------------------------
__global__ __launch_bounds__(256) void bin_kernel(
    const int* __restrict__ src, const int* __restrict__ dst,
    unsigned int* __restrict__ slab, int* __restrict__ slab_cursor)
{
  __shared__ int hist[NBUCK];
  __shared__ int base_s[NBUCK];
  __shared__ int cur[NBUCK];
  const int tid = threadIdx.x;
  const int e0 = blockIdx.x * BIN_CHUNK;
  for (int i = tid; i < NBUCK; i += 256) { hist[i] = 0; cur[i] = 0; }
  __syncthreads();
  for (int i = tid; i < BIN_CHUNK; i += 256) {
    const int e = e0 + i;
    if (e < N_EDGES) atomicAdd(&hist[dst[e] >> BUCK_SHIFT], 1);
  }
  __syncthreads();
  for (int i = tid; i < NBUCK; i += 256) {
    const int h = hist[i];
    base_s[i] = h ? atomicAdd(&slab_cursor[i], h) : 0;
  }
  __syncthreads();
  for (int i = tid; i < BIN_CHUNK; i += 256) {
    const int e = e0 + i;
    if (e >= N_EDGES) continue;
    const int d = dst[e];
    const int bk = d >> BUCK_SHIFT;
    const int p = atomicAdd(&cur[bk], 1);
    int idx = base_s[bk] + p;
    if (idx >= SLABCAP) idx = SLABCAP - 1;   // statistically never
    slab[(size_t)bk * SLABCAP + idx] =
        ((unsigned int)src[e] << BUCK_SHIFT) | (unsigned int)(d & (BUCK_NODES - 1));
  }
}

// ---------------------------------------------------------------------------
// K3: aggregation.  One block per 32-node bucket (1563 blocks).  LDS sort by
// exact dst, then 16-lane quarter-waves own 2 nodes each; single fused pass
// (no max-subtraction), w computed 16-wide then shfl-broadcast, gather x4.
// ---------------------------------------------------------------------------
__global__ __launch_bounds__(256) void aggregate_kernel(
    const half8* __restrict__ feat16, const float* __restrict__ el,
    const float* __restrict__ er,
    const unsigned int* __restrict__ slab, const int* __restrict__ slab_cursor,
    const float* __restrict__ bias, half8* __restrict__ h16)
{
  __shared__ unsigned int csr[SLABCAP];
  __shared__ int cnt_l[BUCK_NODES];
  __shared__ int start_l[BUCK_NODES];
  __shared__ int cur_l[BUCK_NODES];
  const int b = blockIdx.x;
  const int tid = threadIdx.x;
  const int cnt = min(slab_cursor[b], SLABCAP);
  const unsigned int* sb = slab + (size_t)b * SLABCAP;
  const int node0 = b << BUCK_SHIFT;

  if (tid < BUCK_NODES) cnt_l[tid] = 0;
  __syncthreads();
  for (int i = tid; i < cnt; i += 256)
    atomicAdd(&cnt_l[sb[i] & (BUCK_NODES - 1)], 1);
  __syncthreads();
  if (tid < 64) {
    const int v = (tid < BUCK_NODES) ? cnt_l[tid] : 0;
    int inc = v;
#pragma unroll
    for (int d = 1; d < 32; d <<= 1) {
      const int t = __shfl_up(inc, d, 64);
      if (tid >= d) inc += t;
    }
    if (tid < BUCK_NODES) { start_l[tid] = inc - v; cur_l[tid] = 0; }
  }
  __syncthreads();
  for (int i = tid; i < cnt; i += 256) {
    const unsigned int r = sb[i];
    const int p = atomicAdd(&cur_l[r & (BUCK_NODES - 1)], 1);
    csr[start_l[r & (BUCK_NODES - 1)] + p] = r;
  }
  __syncthreads();

  const int lane = tid & 63;
  const int ql = lane & 15;
  const int qb = lane & 48;                      // quarter base lane
  const int qid = (tid >> 6) * 4 + (lane >> 4);  // 0..15
  const float4 b0 = *(const float4*)&bias[ql * 8];
  const float4 b1 = *(const float4*)&bias[ql * 8 + 4];
  const float bb[8] = {b0.x, b0.y, b0.z, b0.w, b1.x, b1.y, b1.z, b1.w};

  for (int nl = qid; nl < BUCK_NODES; nl += 16) {
    const int node = node0 + nl;
    if (node >= N_NODES) break;
    const int beg = start_l[nl];
    const int c = cnt_l[nl];
    const float ern = er[node];

    float sp = 0.f;
    float acc[8];
#pragma unroll
    for (int k = 0; k < 8; ++k) acc[k] = 0.f;

    for (int t0 = 0; t0 < c; t0 += 16) {
      const int t = t0 + ql;
      const unsigned int r = csr[beg + ((t < c) ? t : (c - 1))];
      const int sid = (int)(r >> BUCK_SHIFT);
      float w = 0.f;
      if (t < c) {
        const float v = el[sid] + ern;
        const float e = (v > 0.f) ? v : NEG_SLOPE * v;
        w = __expf(e);
      }
      sp += w;
      const int nb = min(16, c - t0);
      int j = 0;
      for (; j + 4 <= nb; j += 4) {
        float wv[4]; int sv[4]; half8 fv[4];
#pragma unroll
        for (int u = 0; u < 4; ++u) {
          wv[u] = __shfl(w, qb + j + u, 64);
          sv[u] = __shfl(sid, qb + j + u, 64);
        }
#pragma unroll
        for (int u = 0; u < 4; ++u) fv[u] = feat16[(size_t)sv[u] * 16 + ql];
#pragma unroll
        for (int u = 0; u < 4; ++u)
#pragma unroll
          for (int k = 0; k < 8; ++k)
            acc[k] = fmaf(wv[u], (float)fv[u][k], acc[k]);
      }
      for (; j < nb; ++j) {
        const float wj = __shfl(w, qb + j, 64);
        const int sj = __shfl(sid, qb + j, 64);
        const half8 f = feat16[(size_t)sj * 16 + ql];
#pragma unroll
        for (int k = 0; k < 8; ++k) acc[k] = fmaf(wj, (float)f[k], acc[k]);
      }
    }

#pragma unroll
    for (int o = 1; o < 16; o <<= 1) sp += __shfl_xor(sp, o, 64);

    const float inv = (c > 0) ? 1.f / sp : 0.f;
    half8 o;
#pragma unroll
    for (int k = 0; k < 8; ++k)
      o[k] = (_Float16)fmaxf(acc[k] * inv + bb[k], 0.f);
    h16[(size_t)node * 16 + ql] = o;
  }
}

// ---------------------------------------------------------------------------
// K4: scores.  4 pairs per quarter-wave (16 pairs/wave), fp16 rows, 16B loads.
// ---------------------------------------------------------------------------
__global__ __launch_bounds__(256) void score_kernel(
    const half8* __restrict__ h16,
    const int* __restrict__ pos_src, const int* __restrict__ pos_dst,
    const int* __restrict__ neg_src, const int* __restrict__ neg_dst,
    float* __restrict__ out, int ntot)
{
  const int wid = (int)((blockIdx.x * blockDim.x + threadIdx.x) >> 6);
  const int lane = threadIdx.x & 63;
  const int q = lane >> 4;
  const int ql = lane & 15;
  const int base = (wid * 4 + q) * 4;

  int av[4], bv[4];
#pragma unroll
  for (int u = 0; u < 4; ++u) {
    const int p = base + u;
    int a = 0, b = 0;
    if (p < N_POS)      { a = pos_src[p]; b = pos_dst[p]; }
    else if (p < ntot)  { a = neg_src[p - N_POS]; b = neg_dst[p - N_POS]; }
    av[u] = a; bv[u] = b;
  }
  half8 ha[4], hb[4];
#pragma unroll
  for (int u = 0; u < 4; ++u) {
    ha[u] = h16[(size_t)av[u] * 16 + ql];
    hb[u] = h16[(size_t)bv[u] * 16 + ql];
  }
  float sum[4];
#pragma unroll
  for (int u = 0; u < 4; ++u) {
    float s = 0.f;
#pragma unroll
    for (int k = 0; k < 8; ++k) s = fmaf((float)ha[u][k], (float)hb[u][k], s);
#pragma unroll
    for (int o = 8; o > 0; o >>= 1) s += __shfl_xor(s, o, 64);
    sum[u] = s;
  }
  if (ql == 0) {
#pragma unroll
    for (int u = 0; u < 4; ++u) {
      const int p = base + u;
      if (p < ntot) out[p] = sum[u];
    }
  }
}

// ---------------------------------------------------------------------------
extern "C" void kernel_launch(void* const* d_in, const int* in_sizes, int n_in,
                              void* d_out, int out_size, void* d_ws, size_t ws_size,
                              hipStream_t stream) {
  const float* x      = (const float*)d_in[0];
  const float* W      = (const float*)d_in[1];
  const float* attn_l = (const float*)d_in[2];
  const float* attn_r = (const float*)d_in[3];
  const float* bias   = (const float*)d_in[4];
  const int* src      = (const int*)d_in[5];
  const int* dst      = (const int*)d_in[6];
  const int* pos_src  = (const int*)d_in[7];
  const int* pos_dst  = (const int*)d_in[8];
  const int* neg_src  = (const int*)d_in[9];
  const int* neg_dst  = (const int*)d_in[10];
  float* out = (float*)d_out;

  char* ws = (char*)d_ws;
  const size_t F16B = (size_t)N_NODES * DIM * sizeof(_Float16);  // 12.8 MB
  half8* feat16          = (half8*)(ws);
  half8* h16             = (half8*)(ws + F16B);
  float* el              = (float*)(ws + 2 * F16B);
  float* er              = (float*)(ws + 2 * F16B + 200000);
  int*   slab_cursor     = (int*)  (ws + 2 * F16B + 400000);
  unsigned int* slab     = (unsigned int*)(ws + 2 * F16B + 406656);

  hipMemsetAsync(slab_cursor, 0, NBUCK * sizeof(int), stream);

  gemm_feat<<<(N_NODES + 63) / 64, 256, 0, stream>>>(
      x, W, attn_l, attn_r, feat16, el, er, N_NODES);
  bin_kernel<<<NB_BIN, 256, 0, stream>>>(src, dst, slab, slab_cursor);
  aggregate_kernel<<<NBUCK, 256, 0, stream>>>(
      feat16, el, er, slab, slab_cursor, bias, h16);
  score_kernel<<<((N_POS + N_NEG + 15) / 16 + 3) / 4, 256, 0, stream>>>(
      h16, pos_src, pos_dst, neg_src, neg_dst, out, N_POS + N_NEG);
}

// Round 8
// 190.121 us; speedup vs baseline: 1.0965x; 1.0579x over previous
//
#include <hip/hip_runtime.h>
#include <hip/hip_bf16.h>
#include <cstdint>
#include <cstddef>

#define N_NODES 50000
#define N_EDGES 800000
#define N_POS   200000
#define N_NEG   200000
#define DIM     128
#define NEG_SLOPE 0.2f

#define BUCK_SHIFT 5
#define BUCK_NODES 32                        // nodes per bucket
#define NBUCK 1563                           // ceil(50000/32)
#define SLABCAP 768                          // mean 512, sigma 22.6 -> +11 sigma
#define BIN_CHUNK 2048
#define NB_BIN 391                           // ceil(800000/2048)
#define N_EDGE4 200000                       // N_EDGES/4 (exact)

typedef _Float16 half8 __attribute__((ext_vector_type(8)));
typedef float    floatx4 __attribute__((ext_vector_type(4)));

// ---------------------------------------------------------------------------
// K1: feat = x @ W via MFMA fp16 (fp32 accumulate) + fused el/er epilogue.
// Block = 64 rows x 128 cols, 4 waves x 16 rows.  LDS tiles use a 16B-chunk
// XOR swizzle (chunk ^ (row&15)) so fragment ds_read_b128 is ~conflict-free.
// A-frag: A[m=lane&15][k=quad*8+j]; C/D: col=lane&15, row=quad*4+reg.
// ---------------------------------------------------------------------------
__global__ __launch_bounds__(256) void gemm_feat(
    const float* __restrict__ x, const float* __restrict__ W,
    const float* __restrict__ attn_l, const float* __restrict__ attn_r,
    half8* __restrict__ feat16, float* __restrict__ el, float* __restrict__ er,
    int n)
{
  __shared__ _Float16 xt[64 * 128];    // 16 KB, swizzled [row][k]
  __shared__ _Float16 wt[128 * 128];   // 32 KB, swizzled [n][k]  (W^T)
  const int tid = threadIdx.x;
  const int row0 = blockIdx.x * 64;
  const int lane = tid & 63;
  const int wv = tid >> 6;             // wave id 0..3 -> rows [16wv,16wv+16)
  const int ql = lane & 15;
  const int quad = lane >> 4;

  // ---- stage W^T (fp32 -> fp16), transposed scatter into swizzled wt ----
  {
    const int k = tid >> 1;            // 0..127
    const int n0 = (tid & 1) * 64;
#pragma unroll 4
    for (int j = 0; j < 64; j += 4) {
      const float4 v = *(const float4*)&W[(size_t)k * DIM + n0 + j];
      const float vv[4] = {v.x, v.y, v.z, v.w};
#pragma unroll
      for (int u = 0; u < 4; ++u) {
        const int nn = n0 + j + u;
        wt[nn * 128 + ((((k >> 3) ^ (nn & 15)) << 3) | (k & 7))] = (_Float16)vv[u];
      }
    }
  }
  // ---- stage x tile (fp32 -> fp16) into swizzled xt ----
  {
    const int r = tid >> 2;
    const int grow = row0 + r;
    const int c0 = (tid & 3) * 32;
#pragma unroll
    for (int cc = 0; cc < 32; cc += 8) {
      const int c = c0 + cc;
      float4 v0 = make_float4(0.f, 0.f, 0.f, 0.f);
      float4 v1 = make_float4(0.f, 0.f, 0.f, 0.f);
      if (grow < n) {
        const float* sp = &x[(size_t)grow * DIM + c];
        v0 = *(const float4*)(sp);
        v1 = *(const float4*)(sp + 4);
      }
      half8 h;
      h[0] = (_Float16)v0.x; h[1] = (_Float16)v0.y;
      h[2] = (_Float16)v0.z; h[3] = (_Float16)v0.w;
      h[4] = (_Float16)v1.x; h[5] = (_Float16)v1.y;
      h[6] = (_Float16)v1.z; h[7] = (_Float16)v1.w;
      const int chunk = c >> 3;
      *(half8*)&xt[r * 128 + ((chunk ^ (r & 15)) << 3)] = h;
    }
  }
  __syncthreads();

  // ---- MFMA: 8 N-tiles x 4 K-steps ----
  floatx4 acc[8];
#pragma unroll
  for (int t = 0; t < 8; ++t) acc[t] = (floatx4){0.f, 0.f, 0.f, 0.f};

  const int arow = wv * 16 + ql;       // arow & 15 == ql
  half8 af[4];
#pragma unroll
  for (int s = 0; s < 4; ++s) {
    const int chunk = s * 4 + quad;
    af[s] = *(half8*)&xt[arow * 128 + ((chunk ^ ql) << 3)];
  }
#pragma unroll
  for (int t = 0; t < 8; ++t) {
    const int brow = t * 16 + ql;      // brow & 15 == ql
#pragma unroll
    for (int s = 0; s < 4; ++s) {
      const int chunk = s * 4 + quad;
      const half8 bf = *(half8*)&wt[brow * 128 + ((chunk ^ ql) << 3)];
      acc[t] = __builtin_amdgcn_mfma_f32_16x16x32_f16(af[s], bf, acc[t], 0, 0, 0);
    }
  }

  // ---- fused el/er: col = 16t+ql, row = 16wv + 4quad + reg ----
  {
    float al8[8], ar8[8];
#pragma unroll
    for (int t = 0; t < 8; ++t) {
      al8[t] = attn_l[t * 16 + ql];
      ar8[t] = attn_r[t * 16 + ql];
    }
    float pl[4] = {0.f, 0.f, 0.f, 0.f};
    float pr[4] = {0.f, 0.f, 0.f, 0.f};
#pragma unroll
    for (int t = 0; t < 8; ++t)
#pragma unroll
      for (int r = 0; r < 4; ++r) {
        pl[r] = fmaf(acc[t][r], al8[t], pl[r]);
        pr[r] = fmaf(acc[t][r], ar8[t], pr[r]);
      }
#pragma unroll
    for (int o = 1; o < 16; o <<= 1)
#pragma unroll
      for (int r = 0; r < 4; ++r) {
        pl[r] += __shfl_xor(pl[r], o, 64);
        pr[r] += __shfl_xor(pr[r], o, 64);
      }
    if (ql == 0) {
#pragma unroll
      for (int r = 0; r < 4; ++r) {
        const int grow = row0 + wv * 16 + quad * 4 + r;
        if (grow < n) { el[grow] = pl[r]; er[grow] = pr[r]; }
      }
    }
  }

  // ---- feat16 store via LDS bounce (each wave touches only its own rows) --
#pragma unroll
  for (int t = 0; t < 8; ++t)
#pragma unroll
    for (int r = 0; r < 4; ++r)
      xt[(wv * 16 + quad * 4 + r) * 128 + t * 16 + ql] = (_Float16)acc[t][r];
  __syncthreads();
  {
    const int r = tid >> 2;
    const int grow = row0 + r;
    if (grow < n) {
      const int c0 = (tid & 3) * 32;
#pragma unroll
      for (int cc = 0; cc < 32; cc += 8) {
        const half8 h = *(half8*)&xt[r * 128 + c0 + cc];
        feat16[(size_t)grow * 16 + ((c0 + cc) >> 3)] = h;
      }
    }
  }
}

// ---------------------------------------------------------------------------
// K2: bucket binning into 32-node fixed-cap slabs (1563 buckets).
// Record: (src << 5) | (dst & 31).  391 blocks x 2048 edges; each thread owns
// 8 edges via two int4 loads issued up front (short latency chains, MLP).
// ---------------------------------------------------------------------------
__global__ __launch_bounds__(256) void bin_kernel(
    const int4* __restrict__ src4, const int4* __restrict__ dst4,
    unsigned int* __restrict__ slab, int* __restrict__ slab_cursor)
{
  __shared__ int hist[NBUCK];
  __shared__ int base_s[NBUCK];
  __shared__ int cur[NBUCK];
  const int tid = threadIdx.x;
  const int i4base = blockIdx.x * 512;           // int4 units
  const int i40 = i4base + tid;
  const int i41 = i4base + 256 + tid;
  const bool v0 = i40 < N_EDGE4;
  const bool v1 = i41 < N_EDGE4;

  for (int i = tid; i < NBUCK; i += 256) { hist[i] = 0; cur[i] = 0; }
  // issue dst loads before the barrier to overlap with LDS init
  int4 d0 = v0 ? dst4[i40] : make_int4(0, 0, 0, 0);
  int4 d1 = v1 ? dst4[i41] : make_int4(0, 0, 0, 0);
  __syncthreads();

  if (v0) {
    atomicAdd(&hist[d0.x >> BUCK_SHIFT], 1);
    atomicAdd(&hist[d0.y >> BUCK_SHIFT], 1);
    atomicAdd(&hist[d0.z >> BUCK_SHIFT], 1);
    atomicAdd(&hist[d0.w >> BUCK_SHIFT], 1);
  }
  if (v1) {
    atomicAdd(&hist[d1.x >> BUCK_SHIFT], 1);
    atomicAdd(&hist[d1.y >> BUCK_SHIFT], 1);
    atomicAdd(&hist[d1.z >> BUCK_SHIFT], 1);
    atomicAdd(&hist[d1.w >> BUCK_SHIFT], 1);
  }
  // issue src loads before the barrier
  int4 s0 = v0 ? src4[i40] : make_int4(0, 0, 0, 0);
  int4 s1 = v1 ? src4[i41] : make_int4(0, 0, 0, 0);
  __syncthreads();

  for (int i = tid; i < NBUCK; i += 256) {
    const int h = hist[i];
    base_s[i] = h ? atomicAdd(&slab_cursor[i], h) : 0;
  }
  __syncthreads();

  int dd[8] = {d0.x, d0.y, d0.z, d0.w, d1.x, d1.y, d1.z, d1.w};
  int ss[8] = {s0.x, s0.y, s0.z, s0.w, s1.x, s1.y, s1.z, s1.w};
#pragma unroll
  for (int u = 0; u < 8; ++u) {
    if (u < 4 ? v0 : v1) {
      const int d = dd[u];
      const int bk = d >> BUCK_SHIFT;
      const int p = atomicAdd(&cur[bk], 1);
      int idx = base_s[bk] + p;
      if (idx >= SLABCAP) idx = SLABCAP - 1;     // statistically never
      slab[(size_t)bk * SLABCAP + idx] =
          ((unsigned int)ss[u] << BUCK_SHIFT) | (unsigned int)(d & (BUCK_NODES - 1));
    }
  }
}

// ---------------------------------------------------------------------------
// K3: aggregation.  One block per 32-node bucket (1563 blocks).  LDS sort by
// exact dst, then 16-lane quarter-waves own 2 nodes each; single fused pass
// (no max-subtraction), w computed 16-wide then shfl-broadcast, gather x4.
// ---------------------------------------------------------------------------
__global__ __launch_bounds__(256) void aggregate_kernel(
    const half8* __restrict__ feat16, const float* __restrict__ el,
    const float* __restrict__ er,
    const unsigned int* __restrict__ slab, const int* __restrict__ slab_cursor,
    const float* __restrict__ bias, half8* __restrict__ h16)
{
  __shared__ unsigned int csr[SLABCAP];
  __shared__ int cnt_l[BUCK_NODES];
  __shared__ int start_l[BUCK_NODES];
  __shared__ int cur_l[BUCK_NODES];
  const int b = blockIdx.x;
  const int tid = threadIdx.x;
  const int cnt = min(slab_cursor[b], SLABCAP);
  const unsigned int* sb = slab + (size_t)b * SLABCAP;
  const int node0 = b << BUCK_SHIFT;

  if (tid < BUCK_NODES) cnt_l[tid] = 0;
  __syncthreads();
  for (int i = tid; i < cnt; i += 256)
    atomicAdd(&cnt_l[sb[i] & (BUCK_NODES - 1)], 1);
  __syncthreads();
  if (tid < 64) {
    const int v = (tid < BUCK_NODES) ? cnt_l[tid] : 0;
    int inc = v;
#pragma unroll
    for (int d = 1; d < 32; d <<= 1) {
      const int t = __shfl_up(inc, d, 64);
      if (tid >= d) inc += t;
    }
    if (tid < BUCK_NODES) { start_l[tid] = inc - v; cur_l[tid] = 0; }
  }
  __syncthreads();
  for (int i = tid; i < cnt; i += 256) {
    const unsigned int r = sb[i];
    const int p = atomicAdd(&cur_l[r & (BUCK_NODES - 1)], 1);
    csr[start_l[r & (BUCK_NODES - 1)] + p] = r;
  }
  __syncthreads();

  const int lane = tid & 63;
  const int ql = lane & 15;
  const int qb = lane & 48;                      // quarter base lane
  const int qid = (tid >> 6) * 4 + (lane >> 4);  // 0..15
  const float4 b0 = *(const float4*)&bias[ql * 8];
  const float4 b1 = *(const float4*)&bias[ql * 8 + 4];
  const float bb[8] = {b0.x, b0.y, b0.z, b0.w, b1.x, b1.y, b1.z, b1.w};

  for (int nl = qid; nl < BUCK_NODES; nl += 16) {
    const int node = node0 + nl;
    if (node >= N_NODES) break;
    const int beg = start_l[nl];
    const int c = cnt_l[nl];
    const float ern = er[node];

    float sp = 0.f;
    float acc[8];
#pragma unroll
    for (int k = 0; k < 8; ++k) acc[k] = 0.f;

    for (int t0 = 0; t0 < c; t0 += 16) {
      const int t = t0 + ql;
      const unsigned int r = csr[beg + ((t < c) ? t : (c - 1))];
      const int sid = (int)(r >> BUCK_SHIFT);
      float w = 0.f;
      if (t < c) {
        const float v = el[sid] + ern;
        const float e = (v > 0.f) ? v : NEG_SLOPE * v;
        w = __expf(e);
      }
      sp += w;
      const int nb = min(16, c - t0);
      int j = 0;
      for (; j + 4 <= nb; j += 4) {
        float wv[4]; int sv[4]; half8 fv[4];
#pragma unroll
        for (int u = 0; u < 4; ++u) {
          wv[u] = __shfl(w, qb + j + u, 64);
          sv[u] = __shfl(sid, qb + j + u, 64);
        }
#pragma unroll
        for (int u = 0; u < 4; ++u) fv[u] = feat16[(size_t)sv[u] * 16 + ql];
#pragma unroll
        for (int u = 0; u < 4; ++u)
#pragma unroll
          for (int k = 0; k < 8; ++k)
            acc[k] = fmaf(wv[u], (float)fv[u][k], acc[k]);
      }
      for (; j < nb; ++j) {
        const float wj = __shfl(w, qb + j, 64);
        const int sj = __shfl(sid, qb + j, 64);
        const half8 f = feat16[(size_t)sj * 16 + ql];
#pragma unroll
        for (int k = 0; k < 8; ++k) acc[k] = fmaf(wj, (float)f[k], acc[k]);
      }
    }

#pragma unroll
    for (int o = 1; o < 16; o <<= 1) sp += __shfl_xor(sp, o, 64);

    const float inv = (c > 0) ? 1.f / sp : 0.f;
    half8 o;
#pragma unroll
    for (int k = 0; k < 8; ++k)
      o[k] = (_Float16)fmaxf(acc[k] * inv + bb[k], 0.f);
    h16[(size_t)node * 16 + ql] = o;
  }
}

// ---------------------------------------------------------------------------
// K4: scores.  4 pairs per quarter-wave (16 pairs/wave), fp16 rows, 16B loads.
// ---------------------------------------------------------------------------
__global__ __launch_bounds__(256) void score_kernel(
    const half8* __restrict__ h16,
    const int* __restrict__ pos_src, const int* __restrict__ pos_dst,
    const int* __restrict__ neg_src, const int* __restrict__ neg_dst,
    float* __restrict__ out, int ntot)
{
  const int wid = (int)((blockIdx.x * blockDim.x + threadIdx.x) >> 6);
  const int lane = threadIdx.x & 63;
  const int q = lane >> 4;
  const int ql = lane & 15;
  const int base = (wid * 4 + q) * 4;

  int av[4], bv[4];
#pragma unroll
  for (int u = 0; u < 4; ++u) {
    const int p = base + u;
    int a = 0, b = 0;
    if (p < N_POS)      { a = pos_src[p]; b = pos_dst[p]; }
    else if (p < ntot)  { a = neg_src[p - N_POS]; b = neg_dst[p - N_POS]; }
    av[u] = a; bv[u] = b;
  }
  half8 ha[4], hb[4];
#pragma unroll
  for (int u = 0; u < 4; ++u) {
    ha[u] = h16[(size_t)av[u] * 16 + ql];
    hb[u] = h16[(size_t)bv[u] * 16 + ql];
  }
  float sum[4];
#pragma unroll
  for (int u = 0; u < 4; ++u) {
    float s = 0.f;
#pragma unroll
    for (int k = 0; k < 8; ++k) s = fmaf((float)ha[u][k], (float)hb[u][k], s);
#pragma unroll
    for (int o = 8; o > 0; o >>= 1) s += __shfl_xor(s, o, 64);
    sum[u] = s;
  }
  if (ql == 0) {
#pragma unroll
    for (int u = 0; u < 4; ++u) {
      const int p = base + u;
      if (p < ntot) out[p] = sum[u];
    }
  }
}

// ---------------------------------------------------------------------------
extern "C" void kernel_launch(void* const* d_in, const int* in_sizes, int n_in,
                              void* d_out, int out_size, void* d_ws, size_t ws_size,
                              hipStream_t stream) {
  const float* x      = (const float*)d_in[0];
  const float* W      = (const float*)d_in[1];
  const float* attn_l = (const float*)d_in[2];
  const float* attn_r = (const float*)d_in[3];
  const float* bias   = (const float*)d_in[4];
  const int* src      = (const int*)d_in[5];
  const int* dst      = (const int*)d_in[6];
  const int* pos_src  = (const int*)d_in[7];
  const int* pos_dst  = (const int*)d_in[8];
  const int* neg_src  = (const int*)d_in[9];
  const int* neg_dst  = (const int*)d_in[10];
  float* out = (float*)d_out;

  char* ws = (char*)d_ws;
  const size_t F16B = (size_t)N_NODES * DIM * sizeof(_Float16);  // 12.8 MB
  half8* feat16          = (half8*)(ws);
  half8* h16             = (half8*)(ws + F16B);
  float* el              = (float*)(ws + 2 * F16B);
  float* er              = (float*)(ws + 2 * F16B + 200000);
  int*   slab_cursor     = (int*)  (ws + 2 * F16B + 400000);
  unsigned int* slab     = (unsigned int*)(ws + 2 * F16B + 406656);

  hipMemsetAsync(slab_cursor, 0, NBUCK * sizeof(int), stream);

  gemm_feat<<<(N_NODES + 63) / 64, 256, 0, stream>>>(
      x, W, attn_l, attn_r, feat16, el, er, N_NODES);
  bin_kernel<<<NB_BIN, 256, 0, stream>>>(
      (const int4*)src, (const int4*)dst, slab, slab_cursor);
  aggregate_kernel<<<NBUCK, 256, 0, stream>>>(
      feat16, el, er, slab, slab_cursor, bias, h16);
  score_kernel<<<((N_POS + N_NEG + 15) / 16 + 3) / 4, 256, 0, stream>>>(
      h16, pos_src, pos_dst, neg_src, neg_dst, out, N_POS + N_NEG);
}

// Round 9
// 172.736 us; speedup vs baseline: 1.2068x; 1.1006x over previous
//
#include <hip/hip_runtime.h>
#include <hip/hip_bf16.h>
#include <cstdint>
#include <cstddef>

#define N_NODES 50000
#define N_EDGES 800000
#define N_POS   200000
#define N_NEG   200000
#define DIM     128
#define NEG_SLOPE 0.2f

#define BUCK_SHIFT 5
#define BUCK_NODES 32                        // nodes per bucket
#define NBUCK 1563                           // ceil(50000/32)
#define SLABCAP 768                          // mean 512, sigma 22.6 -> +11 sigma
#define NB_BIN 391                           // ceil(800000/2048), 2048 edges/block
#define N_EDGE4 200000                       // N_EDGES/4 (exact)
#define NB_GEMM 782                          // ceil(50000/64)

typedef _Float16 half8 __attribute__((ext_vector_type(8)));
typedef float    floatx4 __attribute__((ext_vector_type(4)));

// ---------------------------------------------------------------------------
// K0: prep.  Zero slab_cursor + build swizzled fp16 W^T in global ws (done
// once, so gemm blocks stage it with plain 16B copies instead of per-block
// transpose+convert).  Swizzle: wt[n*128 + (((k>>3)^(n&15))<<3 | (k&7))].
// ---------------------------------------------------------------------------
__global__ __launch_bounds__(256) void prep_kernel(
    const float* __restrict__ W, _Float16* __restrict__ wt_g,
    int* __restrict__ slab_cursor)
{
  const int tid = threadIdx.x;
  for (int i = blockIdx.x * 256 + tid; i < NBUCK; i += 4 * 256)
    slab_cursor[i] = 0;
  const int k = blockIdx.x * 32 + (tid >> 3);
  const int n0 = (tid & 7) * 16;
#pragma unroll
  for (int j = 0; j < 16; j += 4) {
    const float4 v = *(const float4*)&W[(size_t)k * DIM + n0 + j];
    const float vv[4] = {v.x, v.y, v.z, v.w};
#pragma unroll
    for (int u = 0; u < 4; ++u) {
      const int nn = n0 + j + u;
      wt_g[nn * 128 + ((((k >> 3) ^ (nn & 15)) << 3) | (k & 7))] = (_Float16)vv[u];
    }
  }
}

// ---------------------------------------------------------------------------
// K1: fused gemm + bin.  Blocks [0,391) bin edges; blocks [391,1173) compute
// feat = x @ W via MFMA fp16 + fused el/er.  The two halves are independent;
// bin is latency-bound, gemm is MFMA/LDS-bound -> they co-schedule on CUs.
// ---------------------------------------------------------------------------
__global__ __launch_bounds__(256) void fused_gemm_bin(
    const float* __restrict__ x, const _Float16* __restrict__ wt_g,
    const float* __restrict__ attn_l, const float* __restrict__ attn_r,
    const int4* __restrict__ src4, const int4* __restrict__ dst4,
    half8* __restrict__ feat16, float* __restrict__ el, float* __restrict__ er,
    unsigned int* __restrict__ slab, int* __restrict__ slab_cursor, int n)
{
  __shared__ char smem[49152];
  const int tid = threadIdx.x;

  if (blockIdx.x < NB_BIN) {
    // ---------------- bin path: 2048 edges, 8 per thread via int4 ----------
    int* hist   = (int*)smem;
    int* base_s = hist + NBUCK;
    int* cur    = base_s + NBUCK;
    const int i4base = blockIdx.x * 512;
    const int i40 = i4base + tid;
    const int i41 = i4base + 256 + tid;
    const bool v0 = i40 < N_EDGE4;
    const bool v1 = i41 < N_EDGE4;

    for (int i = tid; i < NBUCK; i += 256) { hist[i] = 0; cur[i] = 0; }
    int4 d0 = v0 ? dst4[i40] : make_int4(0, 0, 0, 0);
    int4 d1 = v1 ? dst4[i41] : make_int4(0, 0, 0, 0);
    __syncthreads();

    if (v0) {
      atomicAdd(&hist[d0.x >> BUCK_SHIFT], 1);
      atomicAdd(&hist[d0.y >> BUCK_SHIFT], 1);
      atomicAdd(&hist[d0.z >> BUCK_SHIFT], 1);
      atomicAdd(&hist[d0.w >> BUCK_SHIFT], 1);
    }
    if (v1) {
      atomicAdd(&hist[d1.x >> BUCK_SHIFT], 1);
      atomicAdd(&hist[d1.y >> BUCK_SHIFT], 1);
      atomicAdd(&hist[d1.z >> BUCK_SHIFT], 1);
      atomicAdd(&hist[d1.w >> BUCK_SHIFT], 1);
    }
    int4 s0 = v0 ? src4[i40] : make_int4(0, 0, 0, 0);
    int4 s1 = v1 ? src4[i41] : make_int4(0, 0, 0, 0);
    __syncthreads();

    for (int i = tid; i < NBUCK; i += 256) {
      const int h = hist[i];
      base_s[i] = h ? atomicAdd(&slab_cursor[i], h) : 0;
    }
    __syncthreads();

    int dd[8] = {d0.x, d0.y, d0.z, d0.w, d1.x, d1.y, d1.z, d1.w};
    int ss[8] = {s0.x, s0.y, s0.z, s0.w, s1.x, s1.y, s1.z, s1.w};
#pragma unroll
    for (int u = 0; u < 8; ++u) {
      if (u < 4 ? v0 : v1) {
        const int d = dd[u];
        const int bk = d >> BUCK_SHIFT;
        const int p = atomicAdd(&cur[bk], 1);
        int idx = base_s[bk] + p;
        if (idx >= SLABCAP) idx = SLABCAP - 1;   // statistically never
        slab[(size_t)bk * SLABCAP + idx] =
            ((unsigned int)ss[u] << BUCK_SHIFT) | (unsigned int)(d & (BUCK_NODES - 1));
      }
    }
    return;
  }

  // ---------------- gemm path: 64 rows x 128 cols, 4 waves x 16 rows -------
  _Float16* xt = (_Float16*)smem;            // 16 KB, swizzled [row][k]
  _Float16* wt = (_Float16*)(smem + 16384);  // 32 KB, swizzled [n][k]
  const int row0 = (blockIdx.x - NB_BIN) * 64;
  const int lane = tid & 63;
  const int wv = tid >> 6;
  const int ql = lane & 15;
  const int quad = lane >> 4;

  // stage W^T: straight 16B copies from prepped global
  {
    const half8* s = (const half8*)wt_g;
    half8* d = (half8*)wt;
#pragma unroll
    for (int i = 0; i < 8; ++i) d[tid + i * 256] = s[tid + i * 256];
  }
  // stage x tile (fp32 -> fp16) into swizzled xt
  {
    const int r = tid >> 2;
    const int grow = row0 + r;
    const int c0 = (tid & 3) * 32;
#pragma unroll
    for (int cc = 0; cc < 32; cc += 8) {
      const int c = c0 + cc;
      float4 v0 = make_float4(0.f, 0.f, 0.f, 0.f);
      float4 v1 = make_float4(0.f, 0.f, 0.f, 0.f);
      if (grow < n) {
        const float* sp = &x[(size_t)grow * DIM + c];
        v0 = *(const float4*)(sp);
        v1 = *(const float4*)(sp + 4);
      }
      half8 h;
      h[0] = (_Float16)v0.x; h[1] = (_Float16)v0.y;
      h[2] = (_Float16)v0.z; h[3] = (_Float16)v0.w;
      h[4] = (_Float16)v1.x; h[5] = (_Float16)v1.y;
      h[6] = (_Float16)v1.z; h[7] = (_Float16)v1.w;
      const int chunk = c >> 3;
      *(half8*)&xt[r * 128 + ((chunk ^ (r & 15)) << 3)] = h;
    }
  }
  __syncthreads();

  floatx4 acc[8];
#pragma unroll
  for (int t = 0; t < 8; ++t) acc[t] = (floatx4){0.f, 0.f, 0.f, 0.f};

  const int arow = wv * 16 + ql;
  half8 af[4];
#pragma unroll
  for (int s = 0; s < 4; ++s) {
    const int chunk = s * 4 + quad;
    af[s] = *(half8*)&xt[arow * 128 + ((chunk ^ ql) << 3)];
  }
#pragma unroll
  for (int t = 0; t < 8; ++t) {
    const int brow = t * 16 + ql;
#pragma unroll
    for (int s = 0; s < 4; ++s) {
      const int chunk = s * 4 + quad;
      const half8 bf = *(half8*)&wt[brow * 128 + ((chunk ^ ql) << 3)];
      acc[t] = __builtin_amdgcn_mfma_f32_16x16x32_f16(af[s], bf, acc[t], 0, 0, 0);
    }
  }

  // fused el/er: col = 16t+ql, row = 16wv + 4quad + reg
  {
    float al8[8], ar8[8];
#pragma unroll
    for (int t = 0; t < 8; ++t) {
      al8[t] = attn_l[t * 16 + ql];
      ar8[t] = attn_r[t * 16 + ql];
    }
    float pl[4] = {0.f, 0.f, 0.f, 0.f};
    float pr[4] = {0.f, 0.f, 0.f, 0.f};
#pragma unroll
    for (int t = 0; t < 8; ++t)
#pragma unroll
      for (int r = 0; r < 4; ++r) {
        pl[r] = fmaf(acc[t][r], al8[t], pl[r]);
        pr[r] = fmaf(acc[t][r], ar8[t], pr[r]);
      }
#pragma unroll
    for (int o = 1; o < 16; o <<= 1)
#pragma unroll
      for (int r = 0; r < 4; ++r) {
        pl[r] += __shfl_xor(pl[r], o, 64);
        pr[r] += __shfl_xor(pr[r], o, 64);
      }
    if (ql == 0) {
#pragma unroll
      for (int r = 0; r < 4; ++r) {
        const int grow = row0 + wv * 16 + quad * 4 + r;
        if (grow < n) { el[grow] = pl[r]; er[grow] = pr[r]; }
      }
    }
  }

  // feat16 store via LDS bounce (each wave touches only its own rows)
#pragma unroll
  for (int t = 0; t < 8; ++t)
#pragma unroll
    for (int r = 0; r < 4; ++r)
      xt[(wv * 16 + quad * 4 + r) * 128 + t * 16 + ql] = (_Float16)acc[t][r];
  __syncthreads();
  {
    const int r = tid >> 2;
    const int grow = row0 + r;
    if (grow < n) {
      const int c0 = (tid & 3) * 32;
#pragma unroll
      for (int cc = 0; cc < 32; cc += 8) {
        const half8 h = *(half8*)&xt[r * 128 + c0 + cc];
        feat16[(size_t)grow * 16 + ((c0 + cc) >> 3)] = h;
      }
    }
  }
}

// ---------------------------------------------------------------------------
// K2: aggregation.  One block per 32-node bucket (1563 blocks).  LDS sort by
// exact dst, then 16-lane quarter-waves own 2 nodes each; single fused pass
// (no max-subtraction), w computed 16-wide then shfl-broadcast, gather x4.
// ---------------------------------------------------------------------------
__global__ __launch_bounds__(256) void aggregate_kernel(
    const half8* __restrict__ feat16, const float* __restrict__ el,
    const float* __restrict__ er,
    const unsigned int* __restrict__ slab, const int* __restrict__ slab_cursor,
    const float* __restrict__ bias, half8* __restrict__ h16)
{
  __shared__ unsigned int csr[SLABCAP];
  __shared__ int cnt_l[BUCK_NODES];
  __shared__ int start_l[BUCK_NODES];
  __shared__ int cur_l[BUCK_NODES];
  const int b = blockIdx.x;
  const int tid = threadIdx.x;
  const int cnt = min(slab_cursor[b], SLABCAP);
  const unsigned int* sb = slab + (size_t)b * SLABCAP;
  const int node0 = b << BUCK_SHIFT;

  if (tid < BUCK_NODES) cnt_l[tid] = 0;
  __syncthreads();
  for (int i = tid; i < cnt; i += 256)
    atomicAdd(&cnt_l[sb[i] & (BUCK_NODES - 1)], 1);
  __syncthreads();
  if (tid < 64) {
    const int v = (tid < BUCK_NODES) ? cnt_l[tid] : 0;
    int inc = v;
#pragma unroll
    for (int d = 1; d < 32; d <<= 1) {
      const int t = __shfl_up(inc, d, 64);
      if (tid >= d) inc += t;
    }
    if (tid < BUCK_NODES) { start_l[tid] = inc - v; cur_l[tid] = 0; }
  }
  __syncthreads();
  for (int i = tid; i < cnt; i += 256) {
    const unsigned int r = sb[i];
    const int p = atomicAdd(&cur_l[r & (BUCK_NODES - 1)], 1);
    csr[start_l[r & (BUCK_NODES - 1)] + p] = r;
  }
  __syncthreads();

  const int lane = tid & 63;
  const int ql = lane & 15;
  const int qb = lane & 48;
  const int qid = (tid >> 6) * 4 + (lane >> 4);
  const float4 b0 = *(const float4*)&bias[ql * 8];
  const float4 b1 = *(const float4*)&bias[ql * 8 + 4];
  const float bb[8] = {b0.x, b0.y, b0.z, b0.w, b1.x, b1.y, b1.z, b1.w};

  for (int nl = qid; nl < BUCK_NODES; nl += 16) {
    const int node = node0 + nl;
    if (node >= N_NODES) break;
    const int beg = start_l[nl];
    const int c = cnt_l[nl];
    const float ern = er[node];

    float sp = 0.f;
    float acc[8];
#pragma unroll
    for (int k = 0; k < 8; ++k) acc[k] = 0.f;

    for (int t0 = 0; t0 < c; t0 += 16) {
      const int t = t0 + ql;
      const unsigned int r = csr[beg + ((t < c) ? t : (c - 1))];
      const int sid = (int)(r >> BUCK_SHIFT);
      float w = 0.f;
      if (t < c) {
        const float v = el[sid] + ern;
        const float e = (v > 0.f) ? v : NEG_SLOPE * v;
        w = __expf(e);
      }
      sp += w;
      const int nb = min(16, c - t0);
      int j = 0;
      for (; j + 4 <= nb; j += 4) {
        float wv[4]; int sv[4]; half8 fv[4];
#pragma unroll
        for (int u = 0; u < 4; ++u) {
          wv[u] = __shfl(w, qb + j + u, 64);
          sv[u] = __shfl(sid, qb + j + u, 64);
        }
#pragma unroll
        for (int u = 0; u < 4; ++u) fv[u] = feat16[(size_t)sv[u] * 16 + ql];
#pragma unroll
        for (int u = 0; u < 4; ++u)
#pragma unroll
          for (int k = 0; k < 8; ++k)
            acc[k] = fmaf(wv[u], (float)fv[u][k], acc[k]);
      }
      for (; j < nb; ++j) {
        const float wj = __shfl(w, qb + j, 64);
        const int sj = __shfl(sid, qb + j, 64);
        const half8 f = feat16[(size_t)sj * 16 + ql];
#pragma unroll
        for (int k = 0; k < 8; ++k) acc[k] = fmaf(wj, (float)f[k], acc[k]);
      }
    }

#pragma unroll
    for (int o = 1; o < 16; o <<= 1) sp += __shfl_xor(sp, o, 64);

    const float inv = (c > 0) ? 1.f / sp : 0.f;
    half8 o;
#pragma unroll
    for (int k = 0; k < 8; ++k)
      o[k] = (_Float16)fmaxf(acc[k] * inv + bb[k], 0.f);
    h16[(size_t)node * 16 + ql] = o;
  }
}

// ---------------------------------------------------------------------------
// K3: scores.  4 pairs per quarter-wave (16 pairs/wave), fp16 rows, 16B loads.
// ---------------------------------------------------------------------------
__global__ __launch_bounds__(256) void score_kernel(
    const half8* __restrict__ h16,
    const int* __restrict__ pos_src, const int* __restrict__ pos_dst,
    const int* __restrict__ neg_src, const int* __restrict__ neg_dst,
    float* __restrict__ out, int ntot)
{
  const int wid = (int)((blockIdx.x * blockDim.x + threadIdx.x) >> 6);
  const int lane = threadIdx.x & 63;
  const int q = lane >> 4;
  const int ql = lane & 15;
  const int base = (wid * 4 + q) * 4;

  int av[4], bv[4];
#pragma unroll
  for (int u = 0; u < 4; ++u) {
    const int p = base + u;
    int a = 0, b = 0;
    if (p < N_POS)      { a = pos_src[p]; b = pos_dst[p]; }
    else if (p < ntot)  { a = neg_src[p - N_POS]; b = neg_dst[p - N_POS]; }
    av[u] = a; bv[u] = b;
  }
  half8 ha[4], hb[4];
#pragma unroll
  for (int u = 0; u < 4; ++u) {
    ha[u] = h16[(size_t)av[u] * 16 + ql];
    hb[u] = h16[(size_t)bv[u] * 16 + ql];
  }
  float sum[4];
#pragma unroll
  for (int u = 0; u < 4; ++u) {
    float s = 0.f;
#pragma unroll
    for (int k = 0; k < 8; ++k) s = fmaf((float)ha[u][k], (float)hb[u][k], s);
#pragma unroll
    for (int o = 8; o > 0; o >>= 1) s += __shfl_xor(s, o, 64);
    sum[u] = s;
  }
  if (ql == 0) {
#pragma unroll
    for (int u = 0; u < 4; ++u) {
      const int p = base + u;
      if (p < ntot) out[p] = sum[u];
    }
  }
}

// ---------------------------------------------------------------------------
extern "C" void kernel_launch(void* const* d_in, const int* in_sizes, int n_in,
                              void* d_out, int out_size, void* d_ws, size_t ws_size,
                              hipStream_t stream) {
  const float* x      = (const float*)d_in[0];
  const float* W      = (const float*)d_in[1];
  const float* attn_l = (const float*)d_in[2];
  const float* attn_r = (const float*)d_in[3];
  const float* bias   = (const float*)d_in[4];
  const int* src      = (const int*)d_in[5];
  const int* dst      = (const int*)d_in[6];
  const int* pos_src  = (const int*)d_in[7];
  const int* pos_dst  = (const int*)d_in[8];
  const int* neg_src  = (const int*)d_in[9];
  const int* neg_dst  = (const int*)d_in[10];
  float* out = (float*)d_out;

  char* ws = (char*)d_ws;
  const size_t F16B = (size_t)N_NODES * DIM * sizeof(_Float16);  // 12.8 MB
  const size_t SLAB_B = (size_t)NBUCK * SLABCAP * sizeof(unsigned int);
  half8* feat16          = (half8*)(ws);
  half8* h16             = (half8*)(ws + F16B);
  float* el              = (float*)(ws + 2 * F16B);
  float* er              = (float*)(ws + 2 * F16B + 200000);
  int*   slab_cursor     = (int*)  (ws + 2 * F16B + 400000);
  unsigned int* slab     = (unsigned int*)(ws + 2 * F16B + 406656);
  _Float16* wt_g         = (_Float16*)(ws + 2 * F16B + 406656 + SLAB_B);

  prep_kernel<<<4, 256, 0, stream>>>(W, wt_g, slab_cursor);
  fused_gemm_bin<<<NB_BIN + NB_GEMM, 256, 0, stream>>>(
      x, wt_g, attn_l, attn_r, (const int4*)src, (const int4*)dst,
      feat16, el, er, slab, slab_cursor, N_NODES);
  aggregate_kernel<<<NBUCK, 256, 0, stream>>>(
      feat16, el, er, slab, slab_cursor, bias, h16);
  score_kernel<<<((N_POS + N_NEG + 15) / 16 + 3) / 4, 256, 0, stream>>>(
      h16, pos_src, pos_dst, neg_src, neg_dst, out, N_POS + N_NEG);
}